// Round 8
// baseline (24649.211 us; speedup 1.0000x reference)
//
#include <hip/hip_runtime.h>
#include <hip/hip_bf16.h>
#include <cstddef>
#include <cstdint>

#define HDIM 512
#define NNODES 1024
#define NEDGES 16384
#define BATCH 32
#define SEQ 1024
#define DIN 128
#define CHUNK 64
#define NCHUNK (SEQ / CHUNK)   // 16
#define GPB 4                  // gemm WGs per batch
#define NSCAN 64               // 32 L0 + 32 L1
#define NWG (NSCAN + BATCH * GPB)   // 192

#define RLX __ATOMIC_RELAXED
#define AGT __HIP_MEMORY_SCOPE_AGENT

// ---------------------------------------------------------------------------
// Prologue: AWp[d][j] = sum_{e: dst_e=d} Wp[src_e][j]
// ---------------------------------------------------------------------------
__global__ void scatter_awp_kernel(const float* __restrict__ Wp,
                                   const int* __restrict__ src,
                                   const int* __restrict__ dst,
                                   float* __restrict__ AWp) {
    int e = blockIdx.x;
    int c = threadIdx.x;
    int s = src[e], d = dst[e];
    atomicAdd(&AWp[d * HDIM + c],       Wp[s * HDIM + c]);
    atomicAdd(&AWp[d * HDIM + 256 + c], Wp[s * HDIM + 256 + c]);
}

__global__ void scatter_abp_kernel(const float* __restrict__ bp,
                                   const int* __restrict__ src,
                                   const int* __restrict__ dst,
                                   float* __restrict__ Abp) {
    int e = blockIdx.x * blockDim.x + threadIdx.x;
    if (e < NEDGES) atomicAdd(&Abp[dst[e]], bp[src[e]]);
}

__global__ void beff_kernel(const float* __restrict__ Wu,
                            const float* __restrict__ Abp,
                            const float* __restrict__ bias,
                            const float* __restrict__ bu,
                            float* __restrict__ beff) {
    int i = threadIdx.x;
    float s = 0.f;
    for (int d = 0; d < NNODES; ++d) s += Wu[i * NNODES + d] * Abp[d];
    beff[i] = bias[i] + bu[i] + s;
}

// 512x512 fp32 transpose (for coalesced GEMM staging of W_in1)
__global__ void transpose_kernel(const float* __restrict__ in,
                                 float* __restrict__ out) {
    __shared__ float tile[32][33];
    int bx = blockIdx.x * 32, by = blockIdx.y * 32;
    int x = threadIdx.x & 31, y = threadIdx.x >> 5;   // 1024 threads
    tile[y][x] = in[(size_t)(by + y) * HDIM + bx + x];
    __syncthreads();
    out[(size_t)(bx + y) * HDIM + by + x] = tile[x][y];
}

// ---------------------------------------------------------------------------
// fp32 tiled GEMM (prologue): C = A @ B (+addend); TB==1 -> B is (N x K)
// ---------------------------------------------------------------------------
template <int TB>
__global__ __launch_bounds__(256) void gemm64(const float* __restrict__ A,
                                              const float* __restrict__ B,
                                              float* __restrict__ C,
                                              const float* __restrict__ addend,
                                              int M, int N, int K) {
    const int bn = blockIdx.x, bm = blockIdx.y;
    const int tid = threadIdx.x;
    const int tx = tid & 15, ty = tid >> 4;
    const int m0 = bm * 64, n0 = bn * 64;

    __shared__ float As[16][68];
    __shared__ float Bs[16][68];

    float acc[4][4] = {};

    for (int k0 = 0; k0 < K; k0 += 16) {
        {
            int kk = tid & 15, m = tid >> 4;
            #pragma unroll
            for (int i = 0; i < 4; ++i)
                As[kk][m + 16 * i] = A[(size_t)(m0 + m + 16 * i) * K + k0 + kk];
        }
        if (TB == 0) {
            int n = tid & 63, kk = tid >> 6;
            #pragma unroll
            for (int i = 0; i < 4; ++i)
                Bs[kk + 4 * i][n] = B[(size_t)(k0 + kk + 4 * i) * N + n0 + n];
        } else {
            int kk = tid & 15, n = tid >> 4;
            #pragma unroll
            for (int i = 0; i < 4; ++i)
                Bs[kk][n + 16 * i] = B[(size_t)(n0 + n + 16 * i) * K + k0 + kk];
        }
        __syncthreads();
        #pragma unroll
        for (int kk = 0; kk < 16; ++kk) {
            float4 a4 = *reinterpret_cast<const float4*>(&As[kk][ty * 4]);
            float4 b4 = *reinterpret_cast<const float4*>(&Bs[kk][tx * 4]);
            float av[4] = {a4.x, a4.y, a4.z, a4.w};
            float bv[4] = {b4.x, b4.y, b4.z, b4.w};
            #pragma unroll
            for (int i = 0; i < 4; ++i)
                #pragma unroll
                for (int j = 0; j < 4; ++j)
                    acc[i][j] += av[i] * bv[j];
        }
        __syncthreads();
    }
    #pragma unroll
    for (int i = 0; i < 4; ++i) {
        int m = m0 + ty * 4 + i;
        #pragma unroll
        for (int j = 0; j < 4; ++j) {
            int n = n0 + tx * 4 + j;
            float v = acc[i][j];
            if (addend) v += addend[(size_t)m * N + n];
            C[(size_t)m * N + n] = v;
        }
    }
}

// ---------------------------------------------------------------------------
// DPP 64-lane sum (validated in R6): lane 63 gets the full 64-lane sum.
// ---------------------------------------------------------------------------
template <int CTRL, int RMASK, bool BC>
__device__ __forceinline__ float dpp_add(float x) {
    int t = __builtin_amdgcn_update_dpp(0, __float_as_int(x), CTRL, RMASK, 0xf, BC);
    return x + __int_as_float(t);
}

__device__ __forceinline__ float reduce64(float x) {
    x = dpp_add<0x111, 0xf, true>(x);   // row_shr:1
    x = dpp_add<0x112, 0xf, true>(x);   // row_shr:2
    x = dpp_add<0x114, 0xf, true>(x);   // row_shr:4
    x = dpp_add<0x118, 0xf, true>(x);   // row_shr:8
    x = dpp_add<0x142, 0xa, false>(x);  // row_bcast:15 -> rows 1,3
    x = dpp_add<0x143, 0xc, false>(x);  // row_bcast:31 -> rows 2,3
    return x;                            // lane 63 = total
}

__device__ __forceinline__ float fast_tanh(float x) {
    float e = __expf(2.0f * x);
    return 1.0f - 2.0f / (e + 1.0f);
}

#define PIN(r) asm volatile("" : "+v"(w[r][0]), "+v"(w[r][1]), "+v"(w[r][2]), \
    "+v"(w[r][3]), "+v"(w[r][4]), "+v"(w[r][5]), "+v"(w[r][6]), "+v"(w[r][7]))

// ---------------------------------------------------------------------------
// Fused kernel, 192 WGs x 1024 threads, all co-resident (1 WG/CU):
//   WG 0..31   : layer-0 scan, batch b = wg      (CU-local recurrence)
//   WG 32..63  : layer-1 scan, batch b = wg-32
//   WG 64..191 : u1-GEMM streamers (4 per batch, chunks of 64 steps)
// Scan: whole W_eff in one CU's VGPRs (w[32][8]/thread, 16 waves);
//   h in LDS transposed (stride 9 -> 2-way-free banks); per step:
//   FMA + DPP reduce64 -> sums in LDS -> 512-thread finisher. No cross-CU
//   traffic in the loop. Chunked release/acquire handshakes (16 per scan):
//   L0 --prog0--> GEMM --flagG--> L1; u1 overwrites consumed u0 in place;
//   ys0 lives in d_out until L1 overwrites it with ys1 (strict DAG ordering).
// ---------------------------------------------------------------------------
__launch_bounds__(1024, 1)
__global__ void fused_kernel(const float* __restrict__ Weff0,
                             const float* __restrict__ beff0,
                             const float* __restrict__ Weff1,
                             const float* __restrict__ beff1,
                             const float* __restrict__ WinT,  // W_in1^T [k][n]
                             float* __restrict__ u_ws,        // (B,S,H) u0 -> u1
                             float* __restrict__ out,         // (B,S,H) ys0 -> ys1
                             unsigned* __restrict__ prog0,    // [B]
                             unsigned* __restrict__ flagG) {  // [B][NCHUNK]
    const int wg = blockIdx.x;
    const int tid = threadIdx.x;
    __shared__ float smem[18944];   // GEMM: As 32x72 + Bs 32x520; scan: 1664

    if (wg < NSCAN) {
        // ===================== scan role =====================
        const int L = wg >> 5;
        const int b = wg & 31;
        const float* Weff = L ? Weff1 : Weff0;
        const float* beff = L ? beff1 : beff0;
        const float lk = L ? 0.15f : 0.10f;
        const float olk = 1.0f - lk;
        const int wv = tid >> 6, lane = tid & 63;
        const int row0 = wv * 32;
        float* hsT  = smem;          // [2][576], row p at (p&63)*9 + (p>>6)
        float* sums = smem + 1152;   // [512]
        float* ub = u_ws + (size_t)b * SEQ * HDIM;
        float* yb = out  + (size_t)b * SEQ * HDIM;

        // full W_eff slice into registers: w[r][k] = Weff[row0+r][lane+64k]
        float w[32][8];
        #pragma unroll
        for (int r = 0; r < 32; ++r)
            #pragma unroll
            for (int k = 0; k < 8; ++k)
                w[r][k] = Weff[(size_t)(row0 + r) * HDIM + lane + 64 * k];
        // one-time pin: post-asm values are opaque -> remat from the global
        // load is illegal; allocator must keep them in VGPRs (or visibly spill)
        PIN(0);  PIN(1);  PIN(2);  PIN(3);  PIN(4);  PIN(5);  PIN(6);  PIN(7);
        PIN(8);  PIN(9);  PIN(10); PIN(11); PIN(12); PIN(13); PIN(14); PIN(15);
        PIN(16); PIN(17); PIN(18); PIN(19); PIN(20); PIN(21); PIN(22); PIN(23);
        PIN(24); PIN(25); PIN(26); PIN(27); PIN(28); PIN(29); PIN(30); PIN(31);

        float be = 0.f, hold = 0.f, u_reg = 0.f;
        if (tid < 512) be = beff[tid];
        if (tid < 576) { hsT[tid] = 0.f; }        // zero parity-0 buffer
        __syncthreads();

        for (int t = 0; t < SEQ; ++t) {
            if ((t & (CHUNK - 1)) == 0) {
                if (L == 1) {   // gate on u1 chunk availability
                    if (tid == 0) {
                        while (__hip_atomic_load(flagG + b * NCHUNK + (t >> 6),
                                                 RLX, AGT) == 0) {}
                        __builtin_amdgcn_fence(__ATOMIC_ACQUIRE, "agent");
                    }
                    __syncthreads();
                }
                if (tid < 512) u_reg = ub[(size_t)t * HDIM + tid];
            }

            const int par = t & 1;
            float h[8];
            #pragma unroll
            for (int k = 0; k < 8; ++k) h[k] = hsT[par * 576 + lane * 9 + k];

            #pragma unroll
            for (int r4 = 0; r4 < 8; ++r4) {
                float s0, s1, s2, s3;
                {
                    const int r = r4 * 4;
                    float a = w[r][0]*h[0] + w[r][1]*h[1] + w[r][2]*h[2] + w[r][3]*h[3]
                            + w[r][4]*h[4] + w[r][5]*h[5] + w[r][6]*h[6] + w[r][7]*h[7];
                    s0 = reduce64(a);
                }
                {
                    const int r = r4 * 4 + 1;
                    float a = w[r][0]*h[0] + w[r][1]*h[1] + w[r][2]*h[2] + w[r][3]*h[3]
                            + w[r][4]*h[4] + w[r][5]*h[5] + w[r][6]*h[6] + w[r][7]*h[7];
                    s1 = reduce64(a);
                }
                {
                    const int r = r4 * 4 + 2;
                    float a = w[r][0]*h[0] + w[r][1]*h[1] + w[r][2]*h[2] + w[r][3]*h[3]
                            + w[r][4]*h[4] + w[r][5]*h[5] + w[r][6]*h[6] + w[r][7]*h[7];
                    s2 = reduce64(a);
                }
                {
                    const int r = r4 * 4 + 3;
                    float a = w[r][0]*h[0] + w[r][1]*h[1] + w[r][2]*h[2] + w[r][3]*h[3]
                            + w[r][4]*h[4] + w[r][5]*h[5] + w[r][6]*h[6] + w[r][7]*h[7];
                    s3 = reduce64(a);
                }
                if (lane == 63)
                    *reinterpret_cast<float4*>(&sums[row0 + r4 * 4]) =
                        make_float4(s0, s1, s2, s3);
            }
            __syncthreads();

            if (tid < 512) {
                float pre = sums[tid] + u_reg + be;
                float hnew = olk * hold + lk * fast_tanh(pre);
                hold = hnew;
                hsT[(par ^ 1) * 576 + (tid & 63) * 9 + (tid >> 6)] = hnew;
                yb[(size_t)t * HDIM + tid] = hnew;     // ys (L0) / final (L1)
                if (((t + 1) & (CHUNK - 1)) != 0 && t + 1 < SEQ)
                    u_reg = ub[(size_t)(t + 1) * HDIM + tid];
            }
            if (L == 0 && ((t + 1) & (CHUNK - 1)) == 0) {
                asm volatile("s_waitcnt vmcnt(0)" ::: "memory");
                __syncthreads();                       // doubles as barrier2
                if (tid == 0) {
                    __builtin_amdgcn_fence(__ATOMIC_RELEASE, "agent");
                    __hip_atomic_store(prog0 + b, (unsigned)((t >> 6) + 1), RLX, AGT);
                }
            } else {
                __syncthreads();                       // barrier2
            }
        }
    } else {
        // ===================== u1-GEMM streamer =====================
        const int g = wg - NSCAN;
        const int b = g & 31;
        const int phase = g >> 5;                      // 0..3
        float* As = smem;                              // [32][72]
        float* Bs = smem + 32 * 72;                    // [32][520]
        const float* yb = out + (size_t)b * SEQ * HDIM;   // ys0
        float* ub = u_ws + (size_t)b * SEQ * HDIM;        // u1 dest (over u0)
        const int tn = tid & 127, tm = tid >> 7;          // 128 x 8

        for (int i = 0; i < 4; ++i) {
            const int c = phase + 4 * i;
            if (tid == 0) {
                while ((int)__hip_atomic_load(prog0 + b, RLX, AGT) < c + 1) {}
                __builtin_amdgcn_fence(__ATOMIC_ACQUIRE, "agent");
            }
            __syncthreads();

            float acc[8][4] = {};
            for (int k0 = 0; k0 < HDIM; k0 += 32) {
                {   // As[kk][m] = ys0[64c+m][k0+kk]
                    int m = tid >> 4, kk = (tid & 15) * 2;
                    float2 v = *reinterpret_cast<const float2*>(
                        yb + (size_t)(c * 64 + m) * HDIM + k0 + kk);
                    As[kk * 72 + m] = v.x;
                    As[(kk + 1) * 72 + m] = v.y;
                }
                {   // Bs[kk][n] = WinT[k0+kk][n] (coalesced)
                    int kk = tid >> 5, n0 = (tid & 31) * 16;
                    const float* wp = WinT + (size_t)(k0 + kk) * HDIM + n0;
                    #pragma unroll
                    for (int q = 0; q < 4; ++q) {
                        float4 v = *reinterpret_cast<const float4*>(wp + 4 * q);
                        *reinterpret_cast<float4*>(&Bs[kk * 520 + n0 + 4 * q]) = v;
                    }
                }
                __syncthreads();
                #pragma unroll 8
                for (int kk = 0; kk < 32; ++kk) {
                    float4 bv = *reinterpret_cast<const float4*>(&Bs[kk * 520 + tn * 4]);
                    #pragma unroll
                    for (int m = 0; m < 8; ++m) {
                        float av = As[kk * 72 + tm * 8 + m];
                        acc[m][0] += av * bv.x;
                        acc[m][1] += av * bv.y;
                        acc[m][2] += av * bv.z;
                        acc[m][3] += av * bv.w;
                    }
                }
                __syncthreads();
            }
            #pragma unroll
            for (int m = 0; m < 8; ++m)
                *reinterpret_cast<float4*>(
                    ub + (size_t)(c * 64 + tm * 8 + m) * HDIM + tn * 4) =
                    make_float4(acc[m][0], acc[m][1], acc[m][2], acc[m][3]);
            asm volatile("s_waitcnt vmcnt(0)" ::: "memory");
            __syncthreads();
            if (tid == 0) {
                __builtin_amdgcn_fence(__ATOMIC_RELEASE, "agent");
                __hip_atomic_store(flagG + b * NCHUNK + c, 1u, RLX, AGT);
            }
        }
    }
}

// ---------------------------------------------------------------------------
extern "C" void kernel_launch(void* const* d_in, const int* in_sizes, int n_in,
                              void* d_out, int out_size, void* d_ws, size_t ws_size,
                              hipStream_t stream) {
    const float* x      = (const float*)d_in[0];
    const int*   edges  = (const int*)d_in[1];
    const float* W_in0  = (const float*)d_in[2];
    const float* W_res0 = (const float*)d_in[3];
    const float* bias0  = (const float*)d_in[4];
    const float* Wp0    = (const float*)d_in[5];
    const float* bp0    = (const float*)d_in[6];
    const float* Wu0    = (const float*)d_in[7];
    const float* bu0    = (const float*)d_in[8];
    const float* W_in1  = (const float*)d_in[9];
    const float* W_res1 = (const float*)d_in[10];
    const float* bias1  = (const float*)d_in[11];
    const float* Wp1    = (const float*)d_in[12];
    const float* bp1    = (const float*)d_in[13];
    const float* Wu1    = (const float*)d_in[14];
    const float* bu1    = (const float*)d_in[15];

    const int* src = edges;
    const int* dst = edges + NEDGES;
    float* out = (float*)d_out;

    // workspace layout
    char* base = (char*)d_ws;
    float* ws_u = (float*)base;                       // u0/u1: 67,108,864
    char* q = base + (size_t)67108864;                // 2,101,248-byte region
    float* AWp = (float*)q;                           // prologue: 2,097,152
    float* Abp = (float*)(q + 2097152);               // prologue: 4,096
    // post-prologue overlay of AWp's space:
    unsigned* prog0 = (unsigned*)q;                   //   128 B
    unsigned* flagG = (unsigned*)(q + 128);           // 2,048 B
    float* WinT = (float*)(q + 4096);                 // 1,048,576 (inside AWp region)
    char* p2 = q + 2101248;
    float* Weff0 = (float*)p2;
    float* Weff1 = (float*)(p2 + 1048576);
    float* beff0 = (float*)(p2 + 2097152);
    float* beff1 = (float*)(p2 + 2099200);

    // ---- layer 0 effective weights ----
    hipMemsetAsync(AWp, 0, 2097152 + 4096, stream);
    scatter_awp_kernel<<<NEDGES, 256, 0, stream>>>(Wp0, src, dst, AWp);
    scatter_abp_kernel<<<NEDGES / 256, 256, 0, stream>>>(bp0, src, dst, Abp);
    gemm64<0><<<dim3(8, 8), 256, 0, stream>>>(Wu0, AWp, Weff0, W_res0, 512, 512, 1024);
    beff_kernel<<<1, 512, 0, stream>>>(Wu0, Abp, bias0, bu0, beff0);

    // ---- layer 1 effective weights ----
    hipMemsetAsync(AWp, 0, 2097152 + 4096, stream);
    scatter_awp_kernel<<<NEDGES, 256, 0, stream>>>(Wp1, src, dst, AWp);
    scatter_abp_kernel<<<NEDGES / 256, 256, 0, stream>>>(bp1, src, dst, Abp);
    gemm64<0><<<dim3(8, 8), 256, 0, stream>>>(Wu1, AWp, Weff1, W_res1, 512, 512, 1024);
    beff_kernel<<<1, 512, 0, stream>>>(Wu1, Abp, bias1, bu1, beff1);

    // ---- u0 = x @ W_in0^T ----
    gemm64<1><<<dim3(512 / 64, 32768 / 64), 256, 0, stream>>>(
        x, W_in0, ws_u, nullptr, BATCH * SEQ, HDIM, DIN);

    // ---- AWp now dead: transpose W_in1 into its region; zero flags ----
    transpose_kernel<<<dim3(16, 16), 1024, 0, stream>>>(W_in1, WinT);
    hipMemsetAsync(q, 0, 2176, stream);   // prog0 + flagG

    // ---- fused dual-layer scan + streamed u1 GEMM ----
    fused_kernel<<<NWG, 1024, 0, stream>>>(Weff0, beff0, Weff1, beff1, WinT,
                                           ws_u, out, prog0, flagG);
}

// Round 9
// 4906.180 us; speedup vs baseline: 5.0241x; 5.0241x over previous
//
#include <hip/hip_runtime.h>
#include <hip/hip_bf16.h>
#include <cstddef>
#include <cstdint>

#define HDIM 512
#define NNODES 1024
#define NEDGES 16384
#define BATCH 32
#define SEQ 1024
#define DIN 128
#define SLICES 8

#define RLX __ATOMIC_RELAXED
#define AGT __HIP_MEMORY_SCOPE_AGENT

// ---------------------------------------------------------------------------
// Prologue: AWp[d][j] = sum_{e: dst_e=d} Wp[src_e][j]
// ---------------------------------------------------------------------------
__global__ void scatter_awp_kernel(const float* __restrict__ Wp,
                                   const int* __restrict__ src,
                                   const int* __restrict__ dst,
                                   float* __restrict__ AWp) {
    int e = blockIdx.x;
    int c = threadIdx.x;
    int s = src[e], d = dst[e];
    atomicAdd(&AWp[d * HDIM + c],       Wp[s * HDIM + c]);
    atomicAdd(&AWp[d * HDIM + 256 + c], Wp[s * HDIM + 256 + c]);
}

__global__ void scatter_abp_kernel(const float* __restrict__ bp,
                                   const int* __restrict__ src,
                                   const int* __restrict__ dst,
                                   float* __restrict__ Abp) {
    int e = blockIdx.x * blockDim.x + threadIdx.x;
    if (e < NEDGES) atomicAdd(&Abp[dst[e]], bp[src[e]]);
}

__global__ void beff_kernel(const float* __restrict__ Wu,
                            const float* __restrict__ Abp,
                            const float* __restrict__ bias,
                            const float* __restrict__ bu,
                            float* __restrict__ beff) {
    int i = threadIdx.x;
    float s = 0.f;
    for (int d = 0; d < NNODES; ++d) s += Wu[i * NNODES + d] * Abp[d];
    beff[i] = bias[i] + bu[i] + s;
}

// ---------------------------------------------------------------------------
// fp32 tiled GEMM (prologue): C = A @ B (+addend); TB==1 -> B is (N x K)
// ---------------------------------------------------------------------------
template <int TB>
__global__ __launch_bounds__(256) void gemm64(const float* __restrict__ A,
                                              const float* __restrict__ B,
                                              float* __restrict__ C,
                                              const float* __restrict__ addend,
                                              int M, int N, int K) {
    const int bn = blockIdx.x, bm = blockIdx.y;
    const int tid = threadIdx.x;
    const int tx = tid & 15, ty = tid >> 4;
    const int m0 = bm * 64, n0 = bn * 64;

    __shared__ float As[16][68];
    __shared__ float Bs[16][68];

    float acc[4][4] = {};

    for (int k0 = 0; k0 < K; k0 += 16) {
        {
            int kk = tid & 15, m = tid >> 4;
            #pragma unroll
            for (int i = 0; i < 4; ++i)
                As[kk][m + 16 * i] = A[(size_t)(m0 + m + 16 * i) * K + k0 + kk];
        }
        if (TB == 0) {
            int n = tid & 63, kk = tid >> 6;
            #pragma unroll
            for (int i = 0; i < 4; ++i)
                Bs[kk + 4 * i][n] = B[(size_t)(k0 + kk + 4 * i) * N + n0 + n];
        } else {
            int kk = tid & 15, n = tid >> 4;
            #pragma unroll
            for (int i = 0; i < 4; ++i)
                Bs[kk][n + 16 * i] = B[(size_t)(n0 + n + 16 * i) * K + k0 + kk];
        }
        __syncthreads();
        #pragma unroll
        for (int kk = 0; kk < 16; ++kk) {
            float4 a4 = *reinterpret_cast<const float4*>(&As[kk][ty * 4]);
            float4 b4 = *reinterpret_cast<const float4*>(&Bs[kk][tx * 4]);
            float av[4] = {a4.x, a4.y, a4.z, a4.w};
            float bv[4] = {b4.x, b4.y, b4.z, b4.w};
            #pragma unroll
            for (int i = 0; i < 4; ++i)
                #pragma unroll
                for (int j = 0; j < 4; ++j)
                    acc[i][j] += av[i] * bv[j];
        }
        __syncthreads();
    }
    #pragma unroll
    for (int i = 0; i < 4; ++i) {
        int m = m0 + ty * 4 + i;
        #pragma unroll
        for (int j = 0; j < 4; ++j) {
            int n = n0 + tx * 4 + j;
            float v = acc[i][j];
            if (addend) v += addend[(size_t)m * N + n];
            C[(size_t)m * N + n] = v;
        }
    }
}

// ---------------------------------------------------------------------------
// DPP half-wave sum (R5-verified): lanes 31/63 hold their 32-lane half sums.
// ---------------------------------------------------------------------------
template <int CTRL, int RMASK, bool BC>
__device__ __forceinline__ float dpp_add(float x) {
    int t = __builtin_amdgcn_update_dpp(0, __float_as_int(x), CTRL, RMASK, 0xf, BC);
    return x + __int_as_float(t);
}

__device__ __forceinline__ float reduce32(float x) {
    x = dpp_add<0x111, 0xf, true>(x);
    x = dpp_add<0x112, 0xf, true>(x);
    x = dpp_add<0x114, 0xf, true>(x);
    x = dpp_add<0x118, 0xf, true>(x);
    x = dpp_add<0x142, 0xa, false>(x);
    return x;
}

__device__ __forceinline__ float fast_tanh(float x) {
    float e = __expf(2.0f * x);
    return 1.0f - 2.0f / (e + 1.0f);
}

// ---------------------------------------------------------------------------
// Recurrent scan, R5 skeleton with LDS-resident weights.
// Grid (8 slices, 32 batch), 512 threads. Thread (hw=tid>>5, c=tid&31):
// rows rowbase..rowbase+3 (rowbase = slice*64 + hw*4), cols {4*(c+32k)}.
// W slice (64x512 fp32 = 128 KB) preloaded once into LDS: guaranteed
// residency (R5/R7/R8 proved VGPR residency is not achievable), per-CU
// bandwidth, immune to cache effects. h exchange: tagged (value,step) 8B
// relaxed agent atomics, parity double-buffer, one barrier per step
// (R3/R5-proven). u prefetched under the poll; h_old kept in storer regs.
// ---------------------------------------------------------------------------
__launch_bounds__(512, 1)
__global__ void scan_kernel(const float* __restrict__ Weff,
                            const float* __restrict__ beff,
                            float* __restrict__ u_ys,               // (B,S,H) in/out
                            unsigned long long* __restrict__ hpair, // [2][B][H]
                            float leak) {
    const int slice = blockIdx.x;   // 0..7
    const int b = blockIdx.y;       // 0..31
    const int tid = threadIdx.x;    // 0..511
    const int c = tid & 31;
    const int hw = tid >> 5;        // 0..15
    const int rloc = hw * 4;        // local row base 0..60
    const int rowbase = slice * 64 + rloc;
    const bool storer = (c == 31);
    const size_t SLOTS = (size_t)BATCH * HDIM;

    __shared__ float wl[64 * HDIM];   // 128 KB weight slice
    __shared__ float hs[2][HDIM];     // parity-buffered h

    // one-time coalesced preload of the weight slice
    {
        const float4* src4 = reinterpret_cast<const float4*>(
            Weff + (size_t)slice * 64 * HDIM);
        float4* dst4 = reinterpret_cast<float4*>(wl);
        #pragma unroll
        for (int i = 0; i < 16; ++i)
            dst4[tid + 512 * i] = src4[tid + 512 * i];
    }

    float4 be4 = make_float4(0.f, 0.f, 0.f, 0.f);
    if (storer) be4 = *reinterpret_cast<const float4*>(beff + rowbase);
    const float lk = leak, olk = 1.0f - leak;
    float* ub = u_ys + (size_t)b * SEQ * HDIM;
    unsigned long long* hb = hpair + (size_t)b * HDIM;
    float4 hold = make_float4(0.f, 0.f, 0.f, 0.f);   // h(0) = 0

    __syncthreads();   // weights staged

    for (int t = 0; t < SEQ; ++t) {
        // u prefetch (storer lanes) -- latency hides under the poll
        float4 u4 = make_float4(0.f, 0.f, 0.f, 0.f);
        if (storer) u4 = *reinterpret_cast<const float4*>(ub + (size_t)t * HDIM + rowbase);

        // poll own slot for tag t (cache-bypassing relaxed agent atomic)
        const unsigned long long* sp = hb + (size_t)(t & 1) * SLOTS + tid;
        unsigned long long v;
        do {
            v = __hip_atomic_load(sp, RLX, AGT);
        } while ((unsigned)(v >> 32) != (unsigned)t);
        hs[t & 1][tid] = __uint_as_float((unsigned)v);
        __syncthreads();

        // 4 rows x 16 cols of FMA; weights from LDS, h from LDS
        float a0 = 0.f, a1 = 0.f, a2 = 0.f, a3 = 0.f;
        const float* hst = hs[t & 1];
        #pragma unroll
        for (int k = 0; k < 4; ++k) {
            const int co = 4 * (c + 32 * k);
            float4 h4 = *reinterpret_cast<const float4*>(hst + co);
            float4 w0 = *reinterpret_cast<const float4*>(&wl[(rloc + 0) * HDIM + co]);
            float4 w1 = *reinterpret_cast<const float4*>(&wl[(rloc + 1) * HDIM + co]);
            float4 w2 = *reinterpret_cast<const float4*>(&wl[(rloc + 2) * HDIM + co]);
            float4 w3 = *reinterpret_cast<const float4*>(&wl[(rloc + 3) * HDIM + co]);
            a0 += w0.x * h4.x + w0.y * h4.y + w0.z * h4.z + w0.w * h4.w;
            a1 += w1.x * h4.x + w1.y * h4.y + w1.z * h4.z + w1.w * h4.w;
            a2 += w2.x * h4.x + w2.y * h4.y + w2.z * h4.z + w2.w * h4.w;
            a3 += w3.x * h4.x + w3.y * h4.y + w3.z * h4.z + w3.w * h4.w;
        }
        a0 = reduce32(a0);
        a1 = reduce32(a1);
        a2 = reduce32(a2);
        a3 = reduce32(a3);

        if (storer) {   // lanes 31/63: row sums for this half-wave's 4 rows
            float n0 = olk * hold.x + lk * fast_tanh(a0 + u4.x + be4.x);
            float n1 = olk * hold.y + lk * fast_tanh(a1 + u4.y + be4.y);
            float n2 = olk * hold.z + lk * fast_tanh(a2 + u4.z + be4.z);
            float n3 = olk * hold.w + lk * fast_tanh(a3 + u4.w + be4.w);
            hold = make_float4(n0, n1, n2, n3);
            unsigned long long tg = ((unsigned long long)(unsigned)(t + 1)) << 32;
            unsigned long long* hw_p = hb + (size_t)((t + 1) & 1) * SLOTS + rowbase;
            __hip_atomic_store(hw_p + 0, tg | __float_as_uint(n0), RLX, AGT);
            __hip_atomic_store(hw_p + 1, tg | __float_as_uint(n1), RLX, AGT);
            __hip_atomic_store(hw_p + 2, tg | __float_as_uint(n2), RLX, AGT);
            __hip_atomic_store(hw_p + 3, tg | __float_as_uint(n3), RLX, AGT);
            *reinterpret_cast<float4*>(ub + (size_t)t * HDIM + rowbase) =
                make_float4(n0, n1, n2, n3);   // ys, in place over u
        }
    }
}

// ---------------------------------------------------------------------------
extern "C" void kernel_launch(void* const* d_in, const int* in_sizes, int n_in,
                              void* d_out, int out_size, void* d_ws, size_t ws_size,
                              hipStream_t stream) {
    const float* x      = (const float*)d_in[0];
    const int*   edges  = (const int*)d_in[1];
    const float* W_in0  = (const float*)d_in[2];
    const float* W_res0 = (const float*)d_in[3];
    const float* bias0  = (const float*)d_in[4];
    const float* Wp0    = (const float*)d_in[5];
    const float* bp0    = (const float*)d_in[6];
    const float* Wu0    = (const float*)d_in[7];
    const float* bu0    = (const float*)d_in[8];
    const float* W_in1  = (const float*)d_in[9];
    const float* W_res1 = (const float*)d_in[10];
    const float* bias1  = (const float*)d_in[11];
    const float* Wp1    = (const float*)d_in[12];
    const float* bp1    = (const float*)d_in[13];
    const float* Wu1    = (const float*)d_in[14];
    const float* bu1    = (const float*)d_in[15];

    const int* src = edges;
    const int* dst = edges + NEDGES;
    float* out = (float*)d_out;

    // workspace layout
    char* base = (char*)d_ws;
    float* ws_u  = (float*)base;                 // 32*1024*512*4 = 67,108,864
    char* p = base + (size_t)67108864;
    float* AWp   = (float*)p;  p += 2097152;     // 1024*512*4
    float* Abp   = (float*)p;  p += 4096;        // 1024*4
    float* Weff0 = (float*)p;  p += 1048576;     // 512*512*4
    float* Weff1 = (float*)p;  p += 1048576;
    float* beff0 = (float*)p;  p += 2048;
    float* beff1 = (float*)p;  p += 2048;
    unsigned long long* hpair = (unsigned long long*)p;  // 2*32*512*8 = 262144
    p += 262144;

    // ---- layer 0 effective weights ----
    hipMemsetAsync(AWp, 0, 2097152 + 4096, stream);
    scatter_awp_kernel<<<NEDGES, 256, 0, stream>>>(Wp0, src, dst, AWp);
    scatter_abp_kernel<<<NEDGES / 256, 256, 0, stream>>>(bp0, src, dst, Abp);
    gemm64<0><<<dim3(8, 8), 256, 0, stream>>>(Wu0, AWp, Weff0, W_res0, 512, 512, 1024);
    beff_kernel<<<1, 512, 0, stream>>>(Wu0, Abp, bias0, bu0, beff0);

    // ---- layer 1 effective weights ----
    hipMemsetAsync(AWp, 0, 2097152 + 4096, stream);
    scatter_awp_kernel<<<NEDGES, 256, 0, stream>>>(Wp1, src, dst, AWp);
    scatter_abp_kernel<<<NEDGES / 256, 256, 0, stream>>>(bp1, src, dst, Abp);
    gemm64<0><<<dim3(8, 8), 256, 0, stream>>>(Wu1, AWp, Weff1, W_res1, 512, 512, 1024);
    beff_kernel<<<1, 512, 0, stream>>>(Wu1, Abp, bias1, bu1, beff1);

    // ---- u0 = x @ W_in0^T ----
    gemm64<1><<<dim3(512 / 64, 32768 / 64), 256, 0, stream>>>(
        x, W_in0, ws_u, nullptr, BATCH * SEQ, HDIM, DIN);

    // ---- layer 0 scan (in place over ws_u) ----
    hipMemsetAsync(hpair, 0, 262144, stream);   // tags 0, h0 = 0
    scan_kernel<<<dim3(SLICES, BATCH), 512, 0, stream>>>(Weff0, beff0, ws_u, hpair, 0.1f);

    // ---- u1 = ys0 @ W_in1^T -> d_out ----
    gemm64<1><<<dim3(512 / 64, 32768 / 64), 256, 0, stream>>>(
        ws_u, W_in1, out, nullptr, BATCH * SEQ, HDIM, HDIM);

    // ---- layer 1 scan (in place over d_out) ----
    hipMemsetAsync(hpair, 0, 262144, stream);
    scan_kernel<<<dim3(SLICES, BATCH), 512, 0, stream>>>(Weff1, beff1, out, hpair, 0.15f);
}

// Round 11
// 3605.777 us; speedup vs baseline: 6.8360x; 1.3606x over previous
//
#include <hip/hip_runtime.h>
#include <hip/hip_bf16.h>
#include <cstddef>
#include <cstdint>

#define HDIM 512
#define NNODES 1024
#define NEDGES 16384
#define BATCH 32
#define SEQ 1024
#define DIN 128
#define SLICES 8

#define RLX __ATOMIC_RELAXED
#define AGT __HIP_MEMORY_SCOPE_AGENT

// ---------------------------------------------------------------------------
// Prologue: AWp[d][j] = sum_{e: dst_e=d} Wp[src_e][j]
// ---------------------------------------------------------------------------
__global__ void scatter_awp_kernel(const float* __restrict__ Wp,
                                   const int* __restrict__ src,
                                   const int* __restrict__ dst,
                                   float* __restrict__ AWp) {
    int e = blockIdx.x;
    int c = threadIdx.x;
    int s = src[e], d = dst[e];
    atomicAdd(&AWp[d * HDIM + c],       Wp[s * HDIM + c]);
    atomicAdd(&AWp[d * HDIM + 256 + c], Wp[s * HDIM + 256 + c]);
}

__global__ void scatter_abp_kernel(const float* __restrict__ bp,
                                   const int* __restrict__ src,
                                   const int* __restrict__ dst,
                                   float* __restrict__ Abp) {
    int e = blockIdx.x * blockDim.x + threadIdx.x;
    if (e < NEDGES) atomicAdd(&Abp[dst[e]], bp[src[e]]);
}

__global__ void beff_kernel(const float* __restrict__ Wu,
                            const float* __restrict__ Abp,
                            const float* __restrict__ bias,
                            const float* __restrict__ bu,
                            float* __restrict__ beff) {
    int i = threadIdx.x;
    float s = 0.f;
    for (int d = 0; d < NNODES; ++d) s += Wu[i * NNODES + d] * Abp[d];
    beff[i] = bias[i] + bu[i] + s;
}

// ---------------------------------------------------------------------------
// fp32 tiled GEMM (prologue): C = A @ B (+addend); TB==1 -> B is (N x K)
// ---------------------------------------------------------------------------
template <int TB>
__global__ __launch_bounds__(256) void gemm64(const float* __restrict__ A,
                                              const float* __restrict__ B,
                                              float* __restrict__ C,
                                              const float* __restrict__ addend,
                                              int M, int N, int K) {
    const int bn = blockIdx.x, bm = blockIdx.y;
    const int tid = threadIdx.x;
    const int tx = tid & 15, ty = tid >> 4;
    const int m0 = bm * 64, n0 = bn * 64;

    __shared__ float As[16][68];
    __shared__ float Bs[16][68];

    float acc[4][4] = {};

    for (int k0 = 0; k0 < K; k0 += 16) {
        {
            int kk = tid & 15, m = tid >> 4;
            #pragma unroll
            for (int i = 0; i < 4; ++i)
                As[kk][m + 16 * i] = A[(size_t)(m0 + m + 16 * i) * K + k0 + kk];
        }
        if (TB == 0) {
            int n = tid & 63, kk = tid >> 6;
            #pragma unroll
            for (int i = 0; i < 4; ++i)
                Bs[kk + 4 * i][n] = B[(size_t)(k0 + kk + 4 * i) * N + n0 + n];
        } else {
            int kk = tid & 15, n = tid >> 4;
            #pragma unroll
            for (int i = 0; i < 4; ++i)
                Bs[kk][n + 16 * i] = B[(size_t)(n0 + n + 16 * i) * K + k0 + kk];
        }
        __syncthreads();
        #pragma unroll
        for (int kk = 0; kk < 16; ++kk) {
            float4 a4 = *reinterpret_cast<const float4*>(&As[kk][ty * 4]);
            float4 b4 = *reinterpret_cast<const float4*>(&Bs[kk][tx * 4]);
            float av[4] = {a4.x, a4.y, a4.z, a4.w};
            float bv[4] = {b4.x, b4.y, b4.z, b4.w};
            #pragma unroll
            for (int i = 0; i < 4; ++i)
                #pragma unroll
                for (int j = 0; j < 4; ++j)
                    acc[i][j] += av[i] * bv[j];
        }
        __syncthreads();
    }
    #pragma unroll
    for (int i = 0; i < 4; ++i) {
        int m = m0 + ty * 4 + i;
        #pragma unroll
        for (int j = 0; j < 4; ++j) {
            int n = n0 + tx * 4 + j;
            float v = acc[i][j];
            if (addend) v += addend[(size_t)m * N + n];
            C[(size_t)m * N + n] = v;
        }
    }
}

// ---------------------------------------------------------------------------
// DPP half-wave sum (R5-verified): lanes 31/63 hold their 32-lane half sums.
// ---------------------------------------------------------------------------
template <int CTRL, int RMASK, bool BC>
__device__ __forceinline__ float dpp_add(float x) {
    int t = __builtin_amdgcn_update_dpp(0, __float_as_int(x), CTRL, RMASK, 0xf, BC);
    return x + __int_as_float(t);
}

__device__ __forceinline__ float reduce32(float x) {
    x = dpp_add<0x111, 0xf, true>(x);
    x = dpp_add<0x112, 0xf, true>(x);
    x = dpp_add<0x114, 0xf, true>(x);
    x = dpp_add<0x118, 0xf, true>(x);
    x = dpp_add<0x142, 0xa, false>(x);
    return x;
}

__device__ __forceinline__ float fast_tanh(float x) {
    float e = __expf(2.0f * x);
    return 1.0f - 2.0f / (e + 1.0f);
}

// ---------------------------------------------------------------------------
// Fused dual-layer scan: 1025 pipelined iterations instead of 2048.
// Grid (8 slices, 32 batch) = 256 WGs x 512 threads, 1 WG/CU (139KB LDS).
// WG(s,b) owns rows 64s..64s+63 of BOTH layers for batch b.
// Iteration i: poll h0 tag i AND h1 tag i-1 (concurrent, latencies overlap);
//   L0 (i<SEQ):  a = Weff0_slice (LDS-resident) . h0(i)   -> h0(i+1) tagged
//   L1 (i>=1):   g = Win1_slice . h0(i) + Weff1_slice . h1(i-1)  [one reduce]
//                -> h1(i) tagged, ys1(i-1) -> out
// Win1/Weff1 slices streamed from L2 each iteration (256KB/CU, ~hides under
// the exchange spin per R5/R9 evidence; 2MB distinct per XCD fits 4MB L2).
// u1 = Win1.ys0 computed locally from the h0 the WG receives anyway -> no
// extra exchange, no extra WGs (R7's failure mode removed). ys0/u1 never
// touch memory; the inter-layer GEMM is gone. Exchange mechanics (tagged 8B
// relaxed agent atomics, parity double-buffer, one barrier/iter) = R3-proven.
// ---------------------------------------------------------------------------
__launch_bounds__(512, 1)
__global__ void scan2_kernel(const float* __restrict__ Weff0,
                             const float* __restrict__ beff0,
                             const float* __restrict__ Weff1,
                             const float* __restrict__ beff1,
                             const float* __restrict__ Win1,   // W_in1 [H][H]
                             const float* __restrict__ u0,     // (B,S,H)
                             float* __restrict__ out,          // (B,S,H) ys1
                             unsigned long long* __restrict__ hp0,  // [2][B][H]
                             unsigned long long* __restrict__ hp1) {// [2][B][H]
    const int slice = blockIdx.x;   // 0..7
    const int b = blockIdx.y;       // 0..31
    const int tid = threadIdx.x;    // 0..511
    const int c = tid & 31;
    const int hw = tid >> 5;        // 0..15
    const int rloc = hw * 4;
    const int rowbase = slice * 64 + rloc;
    const bool storer = (c == 31);
    const size_t SLOTS = (size_t)BATCH * HDIM;

    __shared__ float wl0[64 * HDIM];   // 128 KB resident Weff0 slice
    __shared__ float hs0[2][HDIM];
    __shared__ float hs1[2][HDIM];

    // one-time coalesced preload of the Weff0 slice
    {
        const float4* src4 = reinterpret_cast<const float4*>(
            Weff0 + (size_t)slice * 64 * HDIM);
        float4* dst4 = reinterpret_cast<float4*>(wl0);
        #pragma unroll
        for (int i = 0; i < 16; ++i)
            dst4[tid + 512 * i] = src4[tid + 512 * i];
    }

    float4 be04 = make_float4(0.f, 0.f, 0.f, 0.f);
    float4 be14 = make_float4(0.f, 0.f, 0.f, 0.f);
    if (storer) {
        be04 = *reinterpret_cast<const float4*>(beff0 + rowbase);
        be14 = *reinterpret_cast<const float4*>(beff1 + rowbase);
    }
    const float lk0 = 0.10f, olk0 = 0.90f;
    const float lk1 = 0.15f, olk1 = 0.85f;
    const float* u0b = u0 + (size_t)b * SEQ * HDIM;
    float* ob = out + (size_t)b * SEQ * HDIM;
    unsigned long long* h0b = hp0 + (size_t)b * HDIM;
    unsigned long long* h1b = hp1 + (size_t)b * HDIM;
    float4 hold0 = make_float4(0.f, 0.f, 0.f, 0.f);
    float4 hold1 = make_float4(0.f, 0.f, 0.f, 0.f);

    __syncthreads();   // weights staged

    for (int i = 0; i <= SEQ; ++i) {
        // streamed L1 weights (L2-hot after first pass) -- issue before polls
        float4 wq[4][4], wi[4][4];
        #pragma unroll
        for (int r = 0; r < 4; ++r)
            #pragma unroll
            for (int k = 0; k < 4; ++k) {
                const int co = 4 * (c + 32 * k);
                wq[r][k] = *reinterpret_cast<const float4*>(
                    Weff1 + (size_t)(rowbase + r) * HDIM + co);
                wi[r][k] = *reinterpret_cast<const float4*>(
                    Win1 + (size_t)(rowbase + r) * HDIM + co);
            }
        // u0 prefetch (storer lanes)
        float4 u4 = make_float4(0.f, 0.f, 0.f, 0.f);
        if (storer && i < SEQ)
            u4 = *reinterpret_cast<const float4*>(u0b + (size_t)i * HDIM + rowbase);

        // concurrent polls: h0 tag i, h1 tag i-1
        const unsigned long long* sp0 = h0b + (size_t)(i & 1) * SLOTS + tid;
        const unsigned long long* sp1 = h1b + (size_t)((i - 1) & 1) * SLOTS + tid;
        unsigned long long v0 = __hip_atomic_load(sp0, RLX, AGT);
        unsigned long long v1 = 0ull;
        bool bad0 = ((unsigned)(v0 >> 32) != (unsigned)i);
        bool bad1 = false;
        if (i >= 1) {
            v1 = __hip_atomic_load(sp1, RLX, AGT);
            bad1 = ((unsigned)(v1 >> 32) != (unsigned)(i - 1));
        }
        while (bad0 || bad1) {
            if (bad0) {
                v0 = __hip_atomic_load(sp0, RLX, AGT);
                bad0 = ((unsigned)(v0 >> 32) != (unsigned)i);
            }
            if (bad1) {
                v1 = __hip_atomic_load(sp1, RLX, AGT);
                bad1 = ((unsigned)(v1 >> 32) != (unsigned)(i - 1));
            }
        }
        hs0[i & 1][tid] = __uint_as_float((unsigned)v0);
        if (i >= 1) hs1[(i - 1) & 1][tid] = __uint_as_float((unsigned)v1);
        __syncthreads();

        // ---- L0 step i: a = Weff0_slice . h0(i) ----
        if (i < SEQ) {
            float a0 = 0.f, a1 = 0.f, a2 = 0.f, a3 = 0.f;
            const float* h = hs0[i & 1];
            #pragma unroll
            for (int k = 0; k < 4; ++k) {
                const int co = 4 * (c + 32 * k);
                float4 h4 = *reinterpret_cast<const float4*>(h + co);
                float4 w0 = *reinterpret_cast<const float4*>(&wl0[(rloc + 0) * HDIM + co]);
                float4 w1 = *reinterpret_cast<const float4*>(&wl0[(rloc + 1) * HDIM + co]);
                float4 w2 = *reinterpret_cast<const float4*>(&wl0[(rloc + 2) * HDIM + co]);
                float4 w3 = *reinterpret_cast<const float4*>(&wl0[(rloc + 3) * HDIM + co]);
                a0 += w0.x * h4.x + w0.y * h4.y + w0.z * h4.z + w0.w * h4.w;
                a1 += w1.x * h4.x + w1.y * h4.y + w1.z * h4.z + w1.w * h4.w;
                a2 += w2.x * h4.x + w2.y * h4.y + w2.z * h4.z + w2.w * h4.w;
                a3 += w3.x * h4.x + w3.y * h4.y + w3.z * h4.z + w3.w * h4.w;
            }
            a0 = reduce32(a0);
            a1 = reduce32(a1);
            a2 = reduce32(a2);
            a3 = reduce32(a3);
            if (storer) {
                float n0 = olk0 * hold0.x + lk0 * fast_tanh(a0 + u4.x + be04.x);
                float n1 = olk0 * hold0.y + lk0 * fast_tanh(a1 + u4.y + be04.y);
                float n2 = olk0 * hold0.z + lk0 * fast_tanh(a2 + u4.z + be04.z);
                float n3 = olk0 * hold0.w + lk0 * fast_tanh(a3 + u4.w + be04.w);
                hold0 = make_float4(n0, n1, n2, n3);
                unsigned long long tg = ((unsigned long long)(unsigned)(i + 1)) << 32;
                unsigned long long* hp = h0b + (size_t)((i + 1) & 1) * SLOTS + rowbase;
                __hip_atomic_store(hp + 0, tg | __float_as_uint(n0), RLX, AGT);
                __hip_atomic_store(hp + 1, tg | __float_as_uint(n1), RLX, AGT);
                __hip_atomic_store(hp + 2, tg | __float_as_uint(n2), RLX, AGT);
                __hip_atomic_store(hp + 3, tg | __float_as_uint(n3), RLX, AGT);
            }
        }

        // ---- L1 step i-1: g = Win1.h0(i) + Weff1.h1(i-1), single reduce ----
        if (i >= 1) {
            float g0 = 0.f, g1 = 0.f, g2 = 0.f, g3 = 0.f;
            const float* h0v = hs0[i & 1];          // ys0(i-1) = h0(i)
            const float* h1v = hs1[(i - 1) & 1];
            #pragma unroll
            for (int k = 0; k < 4; ++k) {
                const int co = 4 * (c + 32 * k);
                float4 p4 = *reinterpret_cast<const float4*>(h0v + co);
                float4 q4 = *reinterpret_cast<const float4*>(h1v + co);
                g0 += wi[0][k].x * p4.x + wi[0][k].y * p4.y + wi[0][k].z * p4.z + wi[0][k].w * p4.w
                    + wq[0][k].x * q4.x + wq[0][k].y * q4.y + wq[0][k].z * q4.z + wq[0][k].w * q4.w;
                g1 += wi[1][k].x * p4.x + wi[1][k].y * p4.y + wi[1][k].z * p4.z + wi[1][k].w * p4.w
                    + wq[1][k].x * q4.x + wq[1][k].y * q4.y + wq[1][k].z * q4.z + wq[1][k].w * q4.w;
                g2 += wi[2][k].x * p4.x + wi[2][k].y * p4.y + wi[2][k].z * p4.z + wi[2][k].w * p4.w
                    + wq[2][k].x * q4.x + wq[2][k].y * q4.y + wq[2][k].z * q4.z + wq[2][k].w * q4.w;
                g3 += wi[3][k].x * p4.x + wi[3][k].y * p4.y + wi[3][k].z * p4.z + wi[3][k].w * p4.w
                    + wq[3][k].x * q4.x + wq[3][k].y * q4.y + wq[3][k].z * q4.z + wq[3][k].w * q4.w;
            }
            g0 = reduce32(g0);
            g1 = reduce32(g1);
            g2 = reduce32(g2);
            g3 = reduce32(g3);
            if (storer) {
                float m0 = olk1 * hold1.x + lk1 * fast_tanh(g0 + be14.x);
                float m1 = olk1 * hold1.y + lk1 * fast_tanh(g1 + be14.y);
                float m2 = olk1 * hold1.z + lk1 * fast_tanh(g2 + be14.z);
                float m3 = olk1 * hold1.w + lk1 * fast_tanh(g3 + be14.w);
                hold1 = make_float4(m0, m1, m2, m3);
                unsigned long long tg = ((unsigned long long)(unsigned)i) << 32;
                unsigned long long* hp = h1b + (size_t)(i & 1) * SLOTS + rowbase;
                __hip_atomic_store(hp + 0, tg | __float_as_uint(m0), RLX, AGT);
                __hip_atomic_store(hp + 1, tg | __float_as_uint(m1), RLX, AGT);
                __hip_atomic_store(hp + 2, tg | __float_as_uint(m2), RLX, AGT);
                __hip_atomic_store(hp + 3, tg | __float_as_uint(m3), RLX, AGT);
                *reinterpret_cast<float4*>(ob + (size_t)(i - 1) * HDIM + rowbase) =
                    make_float4(m0, m1, m2, m3);   // ys1
            }
        }
    }
}

// ---------------------------------------------------------------------------
extern "C" void kernel_launch(void* const* d_in, const int* in_sizes, int n_in,
                              void* d_out, int out_size, void* d_ws, size_t ws_size,
                              hipStream_t stream) {
    const float* x      = (const float*)d_in[0];
    const int*   edges  = (const int*)d_in[1];
    const float* W_in0  = (const float*)d_in[2];
    const float* W_res0 = (const float*)d_in[3];
    const float* bias0  = (const float*)d_in[4];
    const float* Wp0    = (const float*)d_in[5];
    const float* bp0    = (const float*)d_in[6];
    const float* Wu0    = (const float*)d_in[7];
    const float* bu0    = (const float*)d_in[8];
    const float* W_in1  = (const float*)d_in[9];
    const float* W_res1 = (const float*)d_in[10];
    const float* bias1  = (const float*)d_in[11];
    const float* Wp1    = (const float*)d_in[12];
    const float* bp1    = (const float*)d_in[13];
    const float* Wu1    = (const float*)d_in[14];
    const float* bu1    = (const float*)d_in[15];

    const int* src = edges;
    const int* dst = edges + NEDGES;
    float* out = (float*)d_out;

    // workspace layout
    char* base = (char*)d_ws;
    float* ws_u  = (float*)base;                 // u0: 67,108,864
    char* p = base + (size_t)67108864;
    float* AWp   = (float*)p;  p += 2097152;     // 1024*512*4
    float* Abp   = (float*)p;  p += 4096;        // 1024*4
    float* Weff0 = (float*)p;  p += 1048576;
    float* Weff1 = (float*)p;  p += 1048576;
    float* beff0 = (float*)p;  p += 2048;
    float* beff1 = (float*)p;  p += 2048;
    unsigned long long* hp0 = (unsigned long long*)p;  p += 262144;
    unsigned long long* hp1 = (unsigned long long*)p;  p += 262144;

    // ---- layer 0 effective weights ----
    hipMemsetAsync(AWp, 0, 2097152 + 4096, stream);
    scatter_awp_kernel<<<NEDGES, 256, 0, stream>>>(Wp0, src, dst, AWp);
    scatter_abp_kernel<<<NEDGES / 256, 256, 0, stream>>>(bp0, src, dst, Abp);
    gemm64<0><<<dim3(8, 8), 256, 0, stream>>>(Wu0, AWp, Weff0, W_res0, 512, 512, 1024);
    beff_kernel<<<1, 512, 0, stream>>>(Wu0, Abp, bias0, bu0, beff0);

    // ---- layer 1 effective weights ----
    hipMemsetAsync(AWp, 0, 2097152 + 4096, stream);
    scatter_awp_kernel<<<NEDGES, 256, 0, stream>>>(Wp1, src, dst, AWp);
    scatter_abp_kernel<<<NEDGES / 256, 256, 0, stream>>>(bp1, src, dst, Abp);
    gemm64<0><<<dim3(8, 8), 256, 0, stream>>>(Wu1, AWp, Weff1, W_res1, 512, 512, 1024);
    beff_kernel<<<1, 512, 0, stream>>>(Wu1, Abp, bias1, bu1, beff1);

    // ---- u0 = x @ W_in0^T ----
    gemm64<1><<<dim3(512 / 64, 32768 / 64), 256, 0, stream>>>(
        x, W_in0, ws_u, nullptr, BATCH * SEQ, HDIM, DIN);

    // ---- fused dual-layer pipelined scan (ys1 straight to d_out) ----
    hipMemsetAsync(hp0, 0, 524288, stream);   // h0(0)=h1(0)=0, tags 0
    scan2_kernel<<<dim3(SLICES, BATCH), 512, 0, stream>>>(
        Weff0, beff0, Weff1, beff1, W_in1, ws_u, out, hp0, hp1);
}

// Round 12
// 3501.164 us; speedup vs baseline: 7.0403x; 1.0299x over previous
//
#include <hip/hip_runtime.h>
#include <hip/hip_bf16.h>
#include <cstddef>
#include <cstdint>

#define HDIM 512
#define NNODES 1024
#define NEDGES 16384
#define BATCH 32
#define SEQ 1024
#define DIN 128
#define SLICES 8

#define RLX __ATOMIC_RELAXED
#define AGT __HIP_MEMORY_SCOPE_AGENT

// ---------------------------------------------------------------------------
// Prologue: AWp[d][j] = sum_{e: dst_e=d} Wp[src_e][j]
// ---------------------------------------------------------------------------
__global__ void scatter_awp_kernel(const float* __restrict__ Wp,
                                   const int* __restrict__ src,
                                   const int* __restrict__ dst,
                                   float* __restrict__ AWp) {
    int e = blockIdx.x;
    int c = threadIdx.x;
    int s = src[e], d = dst[e];
    atomicAdd(&AWp[d * HDIM + c],       Wp[s * HDIM + c]);
    atomicAdd(&AWp[d * HDIM + 256 + c], Wp[s * HDIM + 256 + c]);
}

__global__ void scatter_abp_kernel(const float* __restrict__ bp,
                                   const int* __restrict__ src,
                                   const int* __restrict__ dst,
                                   float* __restrict__ Abp) {
    int e = blockIdx.x * blockDim.x + threadIdx.x;
    if (e < NEDGES) atomicAdd(&Abp[dst[e]], bp[src[e]]);
}

__global__ void beff_kernel(const float* __restrict__ Wu,
                            const float* __restrict__ Abp,
                            const float* __restrict__ bias,
                            const float* __restrict__ bu,
                            float* __restrict__ beff) {
    int i = threadIdx.x;
    float s = 0.f;
    for (int d = 0; d < NNODES; ++d) s += Wu[i * NNODES + d] * Abp[d];
    beff[i] = bias[i] + bu[i] + s;
}

// ---------------------------------------------------------------------------
// fp32 tiled GEMM (prologue): C = A @ B (+addend); TB==1 -> B is (N x K)
// ---------------------------------------------------------------------------
template <int TB>
__global__ __launch_bounds__(256) void gemm64(const float* __restrict__ A,
                                              const float* __restrict__ B,
                                              float* __restrict__ C,
                                              const float* __restrict__ addend,
                                              int M, int N, int K) {
    const int bn = blockIdx.x, bm = blockIdx.y;
    const int tid = threadIdx.x;
    const int tx = tid & 15, ty = tid >> 4;
    const int m0 = bm * 64, n0 = bn * 64;

    __shared__ float As[16][68];
    __shared__ float Bs[16][68];

    float acc[4][4] = {};

    for (int k0 = 0; k0 < K; k0 += 16) {
        {
            int kk = tid & 15, m = tid >> 4;
            #pragma unroll
            for (int i = 0; i < 4; ++i)
                As[kk][m + 16 * i] = A[(size_t)(m0 + m + 16 * i) * K + k0 + kk];
        }
        if (TB == 0) {
            int n = tid & 63, kk = tid >> 6;
            #pragma unroll
            for (int i = 0; i < 4; ++i)
                Bs[kk + 4 * i][n] = B[(size_t)(k0 + kk + 4 * i) * N + n0 + n];
        } else {
            int kk = tid & 15, n = tid >> 4;
            #pragma unroll
            for (int i = 0; i < 4; ++i)
                Bs[kk][n + 16 * i] = B[(size_t)(n0 + n + 16 * i) * K + k0 + kk];
        }
        __syncthreads();
        #pragma unroll
        for (int kk = 0; kk < 16; ++kk) {
            float4 a4 = *reinterpret_cast<const float4*>(&As[kk][ty * 4]);
            float4 b4 = *reinterpret_cast<const float4*>(&Bs[kk][tx * 4]);
            float av[4] = {a4.x, a4.y, a4.z, a4.w};
            float bv[4] = {b4.x, b4.y, b4.z, b4.w};
            #pragma unroll
            for (int i = 0; i < 4; ++i)
                #pragma unroll
                for (int j = 0; j < 4; ++j)
                    acc[i][j] += av[i] * bv[j];
        }
        __syncthreads();
    }
    #pragma unroll
    for (int i = 0; i < 4; ++i) {
        int m = m0 + ty * 4 + i;
        #pragma unroll
        for (int j = 0; j < 4; ++j) {
            int n = n0 + tx * 4 + j;
            float v = acc[i][j];
            if (addend) v += addend[(size_t)m * N + n];
            C[(size_t)m * N + n] = v;
        }
    }
}

// ---------------------------------------------------------------------------
// DPP half-wave sum (R5-verified): lanes 31/63 hold their 32-lane half sums.
// ---------------------------------------------------------------------------
template <int CTRL, int RMASK, bool BC>
__device__ __forceinline__ float dpp_add(float x) {
    int t = __builtin_amdgcn_update_dpp(0, __float_as_int(x), CTRL, RMASK, 0xf, BC);
    return x + __int_as_float(t);
}

__device__ __forceinline__ float reduce32(float x) {
    x = dpp_add<0x111, 0xf, true>(x);
    x = dpp_add<0x112, 0xf, true>(x);
    x = dpp_add<0x114, 0xf, true>(x);
    x = dpp_add<0x118, 0xf, true>(x);
    x = dpp_add<0x142, 0xa, false>(x);
    return x;
}

__device__ __forceinline__ float fast_tanh(float x) {
    float e = __expf(2.0f * x);
    return 1.0f - 2.0f / (e + 1.0f);
}

// ---------------------------------------------------------------------------
// Fused dual-layer scan, R11 + split-barrier chain balancing.
// R11's τ=3.25µs decomposed: the h1 chain (stored at iter end, polled at iter
// top) had ZERO compute overlap -> chain = RTT + L0 + L1. This version gives
// each chain its own barrier phase:
//   top:   poll h0(i) (slack: last iter's L1 phase) + first-try h1 load
//   A      L0 compute, EARLY h0(i+1) store
//   mid:   finalize h1(i-1) poll (slack: poll + L0 phase, first-try reused)
//   B      L1 compute, h1(i) + ys1 store
// -> tau ~= RTT + min(L0 phase, L1 phase). Slot-reuse safety: monotonic-tag
// induction through barrier A (h0) / barrier B (h1): a producer of tag t+2
// first consumed tag t+1 from all peers, which requires every peer thread to
// have passed the barrier following its tag-t consumption. LDS parity reuse
// across 2 iterations is separated by >=3 barriers. All else = R11.
// ---------------------------------------------------------------------------
__launch_bounds__(512, 1)
__global__ void scan2_kernel(const float* __restrict__ Weff0,
                             const float* __restrict__ beff0,
                             const float* __restrict__ Weff1,
                             const float* __restrict__ beff1,
                             const float* __restrict__ Win1,   // W_in1 [H][H]
                             const float* __restrict__ u0,     // (B,S,H)
                             float* __restrict__ out,          // (B,S,H) ys1
                             unsigned long long* __restrict__ hp0,  // [2][B][H]
                             unsigned long long* __restrict__ hp1) {// [2][B][H]
    const int slice = blockIdx.x;   // 0..7
    const int b = blockIdx.y;       // 0..31
    const int tid = threadIdx.x;    // 0..511
    const int c = tid & 31;
    const int hw = tid >> 5;        // 0..15
    const int rloc = hw * 4;
    const int rowbase = slice * 64 + rloc;
    const bool storer = (c == 31);
    const size_t SLOTS = (size_t)BATCH * HDIM;

    __shared__ float wl0[64 * HDIM];   // 128 KB resident Weff0 slice
    __shared__ float hs0[2][HDIM];
    __shared__ float hs1[2][HDIM];

    // one-time coalesced preload of the Weff0 slice
    {
        const float4* src4 = reinterpret_cast<const float4*>(
            Weff0 + (size_t)slice * 64 * HDIM);
        float4* dst4 = reinterpret_cast<float4*>(wl0);
        #pragma unroll
        for (int i = 0; i < 16; ++i)
            dst4[tid + 512 * i] = src4[tid + 512 * i];
    }

    float4 be04 = make_float4(0.f, 0.f, 0.f, 0.f);
    float4 be14 = make_float4(0.f, 0.f, 0.f, 0.f);
    if (storer) {
        be04 = *reinterpret_cast<const float4*>(beff0 + rowbase);
        be14 = *reinterpret_cast<const float4*>(beff1 + rowbase);
    }
    const float lk0 = 0.10f, olk0 = 0.90f;
    const float lk1 = 0.15f, olk1 = 0.85f;
    const float* u0b = u0 + (size_t)b * SEQ * HDIM;
    float* ob = out + (size_t)b * SEQ * HDIM;
    unsigned long long* h0b = hp0 + (size_t)b * HDIM;
    unsigned long long* h1b = hp1 + (size_t)b * HDIM;
    float4 hold0 = make_float4(0.f, 0.f, 0.f, 0.f);
    float4 hold1 = make_float4(0.f, 0.f, 0.f, 0.f);

    __syncthreads();   // weights staged

    for (int i = 0; i <= SEQ; ++i) {
        // streamed L1 weights (L2-hot after first pass) -- issue first
        float4 wq[4][4], wi[4][4];
        #pragma unroll
        for (int r = 0; r < 4; ++r)
            #pragma unroll
            for (int k = 0; k < 4; ++k) {
                const int co = 4 * (c + 32 * k);
                wq[r][k] = *reinterpret_cast<const float4*>(
                    Weff1 + (size_t)(rowbase + r) * HDIM + co);
                wi[r][k] = *reinterpret_cast<const float4*>(
                    Win1 + (size_t)(rowbase + r) * HDIM + co);
            }
        // u0 prefetch (storer lanes)
        float4 u4 = make_float4(0.f, 0.f, 0.f, 0.f);
        if (storer && i < SEQ)
            u4 = *reinterpret_cast<const float4*>(u0b + (size_t)i * HDIM + rowbase);

        const unsigned long long* sp0 = h0b + (size_t)(i & 1) * SLOTS + tid;
        const unsigned long long* sp1 = h1b + (size_t)((i - 1) & 1) * SLOTS + tid;

        // first-attempt h1 load (finalized after L0; usually visible by then)
        unsigned long long v1 = 0ull;
        if (i >= 1) v1 = __hip_atomic_load(sp1, RLX, AGT);

        // poll h0(i): stored early last iteration -> usually ready
        unsigned long long v0 = __hip_atomic_load(sp0, RLX, AGT);
        while ((unsigned)(v0 >> 32) != (unsigned)i)
            v0 = __hip_atomic_load(sp0, RLX, AGT);
        hs0[i & 1][tid] = __uint_as_float((unsigned)v0);
        __syncthreads();   // A: hs0 staged

        // ---- L0 step i: a = Weff0_slice . h0(i); EARLY h0(i+1) store ----
        if (i < SEQ) {
            float a0 = 0.f, a1 = 0.f, a2 = 0.f, a3 = 0.f;
            const float* h = hs0[i & 1];
            #pragma unroll
            for (int k = 0; k < 4; ++k) {
                const int co = 4 * (c + 32 * k);
                float4 h4 = *reinterpret_cast<const float4*>(h + co);
                float4 w0 = *reinterpret_cast<const float4*>(&wl0[(rloc + 0) * HDIM + co]);
                float4 w1 = *reinterpret_cast<const float4*>(&wl0[(rloc + 1) * HDIM + co]);
                float4 w2 = *reinterpret_cast<const float4*>(&wl0[(rloc + 2) * HDIM + co]);
                float4 w3 = *reinterpret_cast<const float4*>(&wl0[(rloc + 3) * HDIM + co]);
                a0 += w0.x * h4.x + w0.y * h4.y + w0.z * h4.z + w0.w * h4.w;
                a1 += w1.x * h4.x + w1.y * h4.y + w1.z * h4.z + w1.w * h4.w;
                a2 += w2.x * h4.x + w2.y * h4.y + w2.z * h4.z + w2.w * h4.w;
                a3 += w3.x * h4.x + w3.y * h4.y + w3.z * h4.z + w3.w * h4.w;
            }
            a0 = reduce32(a0);
            a1 = reduce32(a1);
            a2 = reduce32(a2);
            a3 = reduce32(a3);
            if (storer) {
                float n0 = olk0 * hold0.x + lk0 * fast_tanh(a0 + u4.x + be04.x);
                float n1 = olk0 * hold0.y + lk0 * fast_tanh(a1 + u4.y + be04.y);
                float n2 = olk0 * hold0.z + lk0 * fast_tanh(a2 + u4.z + be04.z);
                float n3 = olk0 * hold0.w + lk0 * fast_tanh(a3 + u4.w + be04.w);
                hold0 = make_float4(n0, n1, n2, n3);
                unsigned long long tg = ((unsigned long long)(unsigned)(i + 1)) << 32;
                unsigned long long* hp = h0b + (size_t)((i + 1) & 1) * SLOTS + rowbase;
                __hip_atomic_store(hp + 0, tg | __float_as_uint(n0), RLX, AGT);
                __hip_atomic_store(hp + 1, tg | __float_as_uint(n1), RLX, AGT);
                __hip_atomic_store(hp + 2, tg | __float_as_uint(n2), RLX, AGT);
                __hip_atomic_store(hp + 3, tg | __float_as_uint(n3), RLX, AGT);
            }
        }

        if (i >= 1) {
            // finalize h1(i-1) poll (first-try issued at top, pre-L0)
            while ((unsigned)(v1 >> 32) != (unsigned)(i - 1))
                v1 = __hip_atomic_load(sp1, RLX, AGT);
            hs1[(i - 1) & 1][tid] = __uint_as_float((unsigned)v1);
        }
        __syncthreads();   // B: hs1 staged

        // ---- L1 step i-1: g = Win1.h0(i) + Weff1.h1(i-1), single reduce ----
        if (i >= 1) {
            float g0 = 0.f, g1 = 0.f, g2 = 0.f, g3 = 0.f;
            const float* h0v = hs0[i & 1];          // ys0(i-1) = h0(i)
            const float* h1v = hs1[(i - 1) & 1];
            #pragma unroll
            for (int k = 0; k < 4; ++k) {
                const int co = 4 * (c + 32 * k);
                float4 p4 = *reinterpret_cast<const float4*>(h0v + co);
                float4 q4 = *reinterpret_cast<const float4*>(h1v + co);
                g0 += wi[0][k].x * p4.x + wi[0][k].y * p4.y + wi[0][k].z * p4.z + wi[0][k].w * p4.w
                    + wq[0][k].x * q4.x + wq[0][k].y * q4.y + wq[0][k].z * q4.z + wq[0][k].w * q4.w;
                g1 += wi[1][k].x * p4.x + wi[1][k].y * p4.y + wi[1][k].z * p4.z + wi[1][k].w * p4.w
                    + wq[1][k].x * q4.x + wq[1][k].y * q4.y + wq[1][k].z * q4.z + wq[1][k].w * q4.w;
                g2 += wi[2][k].x * p4.x + wi[2][k].y * p4.y + wi[2][k].z * p4.z + wi[2][k].w * p4.w
                    + wq[2][k].x * q4.x + wq[2][k].y * q4.y + wq[2][k].z * q4.z + wq[2][k].w * q4.w;
                g3 += wi[3][k].x * p4.x + wi[3][k].y * p4.y + wi[3][k].z * p4.z + wi[3][k].w * p4.w
                    + wq[3][k].x * q4.x + wq[3][k].y * q4.y + wq[3][k].z * q4.z + wq[3][k].w * q4.w;
            }
            g0 = reduce32(g0);
            g1 = reduce32(g1);
            g2 = reduce32(g2);
            g3 = reduce32(g3);
            if (storer) {
                float m0 = olk1 * hold1.x + lk1 * fast_tanh(g0 + be14.x);
                float m1 = olk1 * hold1.y + lk1 * fast_tanh(g1 + be14.y);
                float m2 = olk1 * hold1.z + lk1 * fast_tanh(g2 + be14.z);
                float m3 = olk1 * hold1.w + lk1 * fast_tanh(g3 + be14.w);
                hold1 = make_float4(m0, m1, m2, m3);
                unsigned long long tg = ((unsigned long long)(unsigned)i) << 32;
                unsigned long long* hp = h1b + (size_t)(i & 1) * SLOTS + rowbase;
                __hip_atomic_store(hp + 0, tg | __float_as_uint(m0), RLX, AGT);
                __hip_atomic_store(hp + 1, tg | __float_as_uint(m1), RLX, AGT);
                __hip_atomic_store(hp + 2, tg | __float_as_uint(m2), RLX, AGT);
                __hip_atomic_store(hp + 3, tg | __float_as_uint(m3), RLX, AGT);
                *reinterpret_cast<float4*>(ob + (size_t)(i - 1) * HDIM + rowbase) =
                    make_float4(m0, m1, m2, m3);   // ys1
            }
        }
    }
}

// ---------------------------------------------------------------------------
extern "C" void kernel_launch(void* const* d_in, const int* in_sizes, int n_in,
                              void* d_out, int out_size, void* d_ws, size_t ws_size,
                              hipStream_t stream) {
    const float* x      = (const float*)d_in[0];
    const int*   edges  = (const int*)d_in[1];
    const float* W_in0  = (const float*)d_in[2];
    const float* W_res0 = (const float*)d_in[3];
    const float* bias0  = (const float*)d_in[4];
    const float* Wp0    = (const float*)d_in[5];
    const float* bp0    = (const float*)d_in[6];
    const float* Wu0    = (const float*)d_in[7];
    const float* bu0    = (const float*)d_in[8];
    const float* W_in1  = (const float*)d_in[9];
    const float* W_res1 = (const float*)d_in[10];
    const float* bias1  = (const float*)d_in[11];
    const float* Wp1    = (const float*)d_in[12];
    const float* bp1    = (const float*)d_in[13];
    const float* Wu1    = (const float*)d_in[14];
    const float* bu1    = (const float*)d_in[15];

    const int* src = edges;
    const int* dst = edges + NEDGES;
    float* out = (float*)d_out;

    // workspace layout
    char* base = (char*)d_ws;
    float* ws_u  = (float*)base;                 // u0: 67,108,864
    char* p = base + (size_t)67108864;
    float* AWp   = (float*)p;  p += 2097152;     // 1024*512*4
    float* Abp   = (float*)p;  p += 4096;        // 1024*4
    float* Weff0 = (float*)p;  p += 1048576;
    float* Weff1 = (float*)p;  p += 1048576;
    float* beff0 = (float*)p;  p += 2048;
    float* beff1 = (float*)p;  p += 2048;
    unsigned long long* hp0 = (unsigned long long*)p;  p += 262144;
    unsigned long long* hp1 = (unsigned long long*)p;  p += 262144;

    // ---- layer 0 effective weights ----
    hipMemsetAsync(AWp, 0, 2097152 + 4096, stream);
    scatter_awp_kernel<<<NEDGES, 256, 0, stream>>>(Wp0, src, dst, AWp);
    scatter_abp_kernel<<<NEDGES / 256, 256, 0, stream>>>(bp0, src, dst, Abp);
    gemm64<0><<<dim3(8, 8), 256, 0, stream>>>(Wu0, AWp, Weff0, W_res0, 512, 512, 1024);
    beff_kernel<<<1, 512, 0, stream>>>(Wu0, Abp, bias0, bu0, beff0);

    // ---- layer 1 effective weights ----
    hipMemsetAsync(AWp, 0, 2097152 + 4096, stream);
    scatter_awp_kernel<<<NEDGES, 256, 0, stream>>>(Wp1, src, dst, AWp);
    scatter_abp_kernel<<<NEDGES / 256, 256, 0, stream>>>(bp1, src, dst, Abp);
    gemm64<0><<<dim3(8, 8), 256, 0, stream>>>(Wu1, AWp, Weff1, W_res1, 512, 512, 1024);
    beff_kernel<<<1, 512, 0, stream>>>(Wu1, Abp, bias1, bu1, beff1);

    // ---- u0 = x @ W_in0^T ----
    gemm64<1><<<dim3(512 / 64, 32768 / 64), 256, 0, stream>>>(
        x, W_in0, ws_u, nullptr, BATCH * SEQ, HDIM, DIN);

    // ---- fused dual-layer pipelined scan (ys1 straight to d_out) ----
    hipMemsetAsync(hp0, 0, 524288, stream);   // h0(0)=h1(0)=0, tags 0
    scan2_kernel<<<dim3(SLICES, BATCH), 512, 0, stream>>>(
        Weff0, beff0, Weff1, beff1, W_in1, ws_u, out, hp0, hp1);
}